// Round 20
// baseline (201.707 us; speedup 1.0000x reference)
//
#include <hip/hip_runtime.h>

#define NN    4096
#define MM    8191   // 2*NN - 1 (valid rows 0..8190)
#define BB    256
#define NRT   256    // row tiles of 32

typedef short bf16x8 __attribute__((ext_vector_type(8)));
typedef float f32x4  __attribute__((ext_vector_type(4)));

// round-to-nearest-even pack of two f32 -> 2x bf16 in one uint
__device__ __forceinline__ unsigned pack2bf(float lo, float hi) {
    unsigned a = __float_as_uint(lo);
    unsigned b = __float_as_uint(hi);
    a += 0x7fffu + ((a >> 16) & 1u);
    b += 0x7fffu + ((b >> 16) & 1u);
    return (a >> 16) | (b & 0xffff0000u);
}

// 8 f32 (0/1-valued) -> 8 bf16 by truncation (exact for 0/1)
__device__ __forceinline__ bf16x8 cvt8(float4 a, float4 b) {
    bf16x8 r;
    r[0] = (short)(__float_as_uint(a.x) >> 16);
    r[1] = (short)(__float_as_uint(a.y) >> 16);
    r[2] = (short)(__float_as_uint(a.z) >> 16);
    r[3] = (short)(__float_as_uint(a.w) >> 16);
    r[4] = (short)(__float_as_uint(b.x) >> 16);
    r[5] = (short)(__float_as_uint(b.y) >> 16);
    r[6] = (short)(__float_as_uint(b.z) >> 16);
    r[7] = (short)(__float_as_uint(b.w) >> 16);
    return r;
}

// ---------------------------------------------------------------------------
// k_prep: ddt[b][n] = bf16(d1[n][b]-d2[n][b]) (2 MB, transposed: B-operand
// k-contiguous per column). Coalesced reads, 32 B/thread writes.
// ---------------------------------------------------------------------------
__global__ __launch_bounds__(256) void k_prep(const float* __restrict__ d1,
                                              const float* __restrict__ d2,
                                              char* __restrict__ ddt) {
    const int bn = blockIdx.x;
    const int b  = threadIdx.x;
    const int n0 = bn * 16;
    float df[16];
    #pragma unroll
    for (int j = 0; j < 16; ++j) {
        int idx = (n0 + j) * BB + b;
        df[j] = d1[idx] - d2[idx];
    }
    uint4 w0, w1;
    w0.x = pack2bf(df[0], df[1]);   w0.y = pack2bf(df[2], df[3]);
    w0.z = pack2bf(df[4], df[5]);   w0.w = pack2bf(df[6], df[7]);
    w1.x = pack2bf(df[8], df[9]);   w1.y = pack2bf(df[10], df[11]);
    w1.z = pack2bf(df[12], df[13]); w1.w = pack2bf(df[14], df[15]);
    uint4* dst = (uint4*)(ddt + (size_t)b * (NN * 2) + n0 * 2);
    dst[0] = w0;
    dst[1] = w1;
}

// ---------------------------------------------------------------------------
// k_gemm v2 (R19 post-mortem: 256 blocks = 1/CU -> zero cross-block TLP and
// per-iter serialized stage loads). Changes: (1) K-split x2 -> 512 blocks =
// 2 blocks/CU, A-traffic unchanged 134 MB; (2) stage loads batched into regs
// (one vmcnt group, overlapping the A HBM loads), ds_write after MFMAs;
// (3) raw acc written to mdp (k_post applies wv*|.|). Inner loop + layout
// mapping identical to the absmax-0-verified R19 kernel.
// ---------------------------------------------------------------------------
__global__ __launch_bounds__(512) void k_gemm(
        const float* __restrict__ subtree,
        const char* __restrict__ ddt,
        char* __restrict__ mdp,
        int ksplit, int usef32) {
    __shared__ uint4 lds_b[2][2048];     // 2 x 32 KB B-chunks
    const int tid = threadIdx.x;
    const int w   = tid >> 6;
    const int l   = tid & 63;
    const int rb  = w & 1;
    const int cb  = w >> 1;
    const int rt  = (ksplit == 2) ? (blockIdx.x & 255) : blockIdx.x;
    const int kh  = (ksplit == 2) ? (blockIdx.x >> 8) : 0;
    const int m0  = rt * 32;
    const int kbase = kh * 2048;
    const int nstep = (ksplit == 2) ? 32 : 64;

    int rowg = m0 + rb * 16 + (l & 15);
    if (rowg >= MM) rowg = MM - 1;
    const float4* Arow = (const float4*)(subtree + (size_t)rowg * NN + kbase)
                         + (l >> 4) * 2;

    #define SLOAD(k0, R)                                                     \
    {                                                                        \
        _Pragma("unroll")                                                    \
        for (int i = 0; i < 4; ++i) {                                        \
            int S = tid + i * 512, col = S >> 3, j16 = S & 7;                \
            R[i] = *(const uint4*)(ddt + (size_t)col * (NN * 2)              \
                   + (size_t)(kbase + (k0)) * 2 + ((j16 ^ (col & 7)) << 4)); \
        }                                                                    \
    }
    #define SWRITE(bufsel, R)                                                \
    {                                                                        \
        _Pragma("unroll")                                                    \
        for (int i = 0; i < 4; ++i) lds_b[bufsel][tid + i * 512] = R[i];     \
    }

    f32x4 acc[4] = {{0,0,0,0},{0,0,0,0},{0,0,0,0},{0,0,0,0}};
    uint4 st[4];

    SLOAD(0, st);
    SWRITE(0, st);
    __syncthreads();

    int buf = 0;
    #pragma unroll 1
    for (int t = 0; t < nstep; ++t) {
        const int k0 = t * 64;
        if (t + 1 < nstep) SLOAD(k0 + 64, st);   // issue early (one group)

        const float4* Ap = Arow + (k0 >> 2);
        float4 u00 = Ap[0], u01 = Ap[1];
        float4 u10 = Ap[8], u11 = Ap[9];
        bf16x8 a0 = cvt8(u00, u01);
        bf16x8 a1 = cvt8(u10, u11);

        const char* B = (const char*)lds_b[buf];
        #pragma unroll
        for (int f = 0; f < 4; ++f) {
            int col = cb * 64 + f * 16 + (l & 15);
            int c7  = col & 7;
            bf16x8 b0 = *(const bf16x8*)(B + col * 128 + ((((l >> 4))     ^ c7) << 4));
            bf16x8 b1 = *(const bf16x8*)(B + col * 128 + (((4 + (l >> 4)) ^ c7) << 4));
            acc[f] = __builtin_amdgcn_mfma_f32_16x16x32_bf16(a0, b0, acc[f], 0, 0, 0);
            acc[f] = __builtin_amdgcn_mfma_f32_16x16x32_bf16(a1, b1, acc[f], 0, 0, 0);
        }
        if (t + 1 < nstep) SWRITE(buf ^ 1, st);
        __syncthreads();
        buf ^= 1;
    }
    #undef SLOAD
    #undef SWRITE

    // write raw partial md (C/D layout: col=lane&15, row=(lane>>4)*4+reg)
    if (usef32) {
        float* mp = (float*)mdp + (size_t)kh * 8192 * BB;
        #pragma unroll
        for (int f = 0; f < 4; ++f) {
            int col = cb * 64 + f * 16 + (l & 15);
            #pragma unroll
            for (int r = 0; r < 4; ++r) {
                int row = m0 + rb * 16 + (l >> 4) * 4 + r;
                mp[(size_t)row * BB + col] = acc[f][r];
            }
        }
    } else {
        unsigned short* mp = (unsigned short*)mdp + (size_t)kh * 8192 * BB;
        #pragma unroll
        for (int f = 0; f < 4; ++f) {
            int col = cb * 64 + f * 16 + (l & 15);
            #pragma unroll
            for (int r = 0; r < 4; ++r) {
                int row = m0 + rb * 16 + (l >> 4) * 4 + r;
                unsigned u = __float_as_uint(acc[f][r]);
                u += 0x7fffu + ((u >> 16) & 1u);
                mp[(size_t)row * BB + col] = (unsigned short)(u >> 16);
            }
        }
    }
}

// ---------------------------------------------------------------------------
// k_post: 512 blocks x 256 thr; block p: rows p*16..+15, thread = col.
// md = sum of ksplit partials; part2[p][col] = sum_rows wv[m]*|md|.
// Fully coalesced (row-major mdp, tid along col).
// ---------------------------------------------------------------------------
__global__ __launch_bounds__(256) void k_post(const char* __restrict__ mdp,
                                              const float* __restrict__ param,
                                              const int*   __restrict__ parents,
                                              float* __restrict__ part2,
                                              int ksplit, int usef32) {
    __shared__ float wv_s[16];
    const int p = blockIdx.x, tid = threadIdx.x;
    if (tid < 16) {
        int m = p * 16 + tid;
        wv_s[tid] = (m < MM) ? (param[parents[m]] - param[m]) : 0.0f;
    }
    __syncthreads();
    float s = 0.0f;
    #pragma unroll 4
    for (int j = 0; j < 16; ++j) {
        int m = p * 16 + j;
        if (m >= MM) break;
        float v;
        if (usef32) {
            const float* mp = (const float*)mdp;
            v = mp[(size_t)m * BB + tid];
            if (ksplit == 2) v += mp[(size_t)8192 * BB + (size_t)m * BB + tid];
        } else {
            const unsigned short* mp = (const unsigned short*)mdp;
            v = __uint_as_float((unsigned)mp[(size_t)m * BB + tid] << 16);
            if (ksplit == 2)
                v += __uint_as_float(
                    (unsigned)mp[(size_t)8192 * BB + (size_t)m * BB + tid] << 16);
        }
        s += wv_s[j] * fabsf(v);
    }
    part2[(size_t)p * BB + tid] = s;
}

// ---------------------------------------------------------------------------
// k_finalize: 1024 thr; (sl,b): sl sums 128 of the 512 part2 rows 8-deep;
// LDS-reduce; out = sum_b (ot[b] - 0.5*w1[b])^2.
// ---------------------------------------------------------------------------
__global__ __launch_bounds__(1024) void k_finalize(const float* __restrict__ part2,
                                                   const float* __restrict__ ot,
                                                   float* __restrict__ out) {
    __shared__ float s_red[4][BB];
    __shared__ float s_sq[16];
    const int tid = threadIdx.x;
    const int sl = tid >> 8, b = tid & 255;

    float a0 = 0.f, a1 = 0.f, a2 = 0.f, a3 = 0.f;
    float a4 = 0.f, a5 = 0.f, a6 = 0.f, a7 = 0.f;
    #pragma unroll
    for (int jj = 0; jj < 128; jj += 8) {
        int row = sl * 128 + jj;
        a0 += part2[(row    ) * BB + b];
        a1 += part2[(row + 1) * BB + b];
        a2 += part2[(row + 2) * BB + b];
        a3 += part2[(row + 3) * BB + b];
        a4 += part2[(row + 4) * BB + b];
        a5 += part2[(row + 5) * BB + b];
        a6 += part2[(row + 6) * BB + b];
        a7 += part2[(row + 7) * BB + b];
    }
    s_red[sl][b] = ((a0 + a1) + (a2 + a3)) + ((a4 + a5) + (a6 + a7));
    __syncthreads();

    float v = 0.0f;
    if (sl == 0) {
        float w1 = (s_red[0][b] + s_red[1][b]) + (s_red[2][b] + s_red[3][b]);
        float e = ot[b] - 0.5f * w1;
        v = e * e;
    }
    #pragma unroll
    for (int off = 32; off > 0; off >>= 1) v += __shfl_down(v, off, 64);
    if ((tid & 63) == 0) s_sq[tid >> 6] = v;
    __syncthreads();
    if (tid == 0) out[0] = (s_sq[0] + s_sq[1]) + (s_sq[2] + s_sq[3]);
}

// ---------------------------------------------------------------------------
extern "C" void kernel_launch(void* const* d_in, const int* in_sizes, int n_in,
                              void* d_out, int out_size, void* d_ws, size_t ws_size,
                              hipStream_t stream) {
    const float* d1      = (const float*)d_in[0];
    const float* d2      = (const float*)d_in[1];
    const float* ot      = (const float*)d_in[2];
    const float* subtree = (const float*)d_in[3];
    const float* param   = (const float*)d_in[4];
    const int*   parents = (const int*)d_in[5];

    char* wsb = (char*)d_ws;
    const size_t ddtb  = (size_t)BB * NN * 2;          // 2 MB
    const size_t mdp2  = (size_t)2 * 8192 * BB * 4;    // 16.78 MB f32 x2
    const size_t mdp1b = (size_t)8192 * BB * 2;        // 4.19 MB bf16 x1
    const size_t p2b   = (size_t)512 * BB * 4;         // 512 KB

    int ksplit, usef32;
    size_t mdpbytes;
    if (ws_size >= ddtb + mdp2 + p2b) { ksplit = 2; usef32 = 1; mdpbytes = mdp2; }
    else                              { ksplit = 1; usef32 = 0; mdpbytes = mdp1b; }

    char*  ddt   = wsb;
    char*  mdp   = wsb + ddtb;
    float* part2 = (float*)(wsb + ddtb + mdpbytes);

    k_prep<<<256, 256, 0, stream>>>(d1, d2, ddt);
    k_gemm<<<NRT * ksplit, 512, 0, stream>>>(subtree, ddt, mdp, ksplit, usef32);
    k_post<<<512, 256, 0, stream>>>(mdp, param, parents, part2, ksplit, usef32);
    k_finalize<<<1, 1024, 0, stream>>>(part2, ot, (float*)d_out);
}

// Round 21
// 47.553 us; speedup vs baseline: 4.2418x; 4.2418x over previous
//
#include <hip/hip_runtime.h>
#include <hip/hip_fp8.h>

#define NN    4096
#define MM    8191   // 2*NN - 1
#define BB    256
#define CAP   256    // u16 slots per row (nnz/row ~41, max ~70; +7 pad)
#define ZROW  4096   // sentinel zero-row index in dd8

typedef float nfloat4 __attribute__((ext_vector_type(4)));
typedef float f32x2 __attribute__((ext_vector_type(2)));

__device__ __forceinline__ int prefix_lt(unsigned long long m) {
    return __builtin_amdgcn_mbcnt_hi((unsigned)(m >> 32),
           __builtin_amdgcn_mbcnt_lo((unsigned)m, 0u));
}

#if defined(__has_builtin)
#if __has_builtin(__builtin_amdgcn_cvt_pk_fp8_f32) && __has_builtin(__builtin_amdgcn_cvt_pk_f32_fp8)
#define HW_FP8 1
#endif
#endif

// pack 4 f32 -> 4x e4m3 in one uint (cols 0..3 = bytes 0..3)
__device__ __forceinline__ unsigned pack4fp8(float x0, float x1, float x2, float x3) {
#ifdef HW_FP8
    int r = 0;
    r = __builtin_amdgcn_cvt_pk_fp8_f32(x0, x1, r, false);
    r = __builtin_amdgcn_cvt_pk_fp8_f32(x2, x3, r, true);
    return (unsigned)r;
#else
    __hip_fp8_e4m3 a(x0), b(x1), c(x2), d(x3);
    return (unsigned)a.__x | ((unsigned)b.__x << 8) |
           ((unsigned)c.__x << 16) | ((unsigned)d.__x << 24);
#endif
}

// ---------------------------------------------------------------------------
// k_prep: zero part2[256*256]; dd8 = fp8(d1-d2) (1 MB) + sentinel zero-row.
// ---------------------------------------------------------------------------
__global__ __launch_bounds__(256) void k_prep(const float4* __restrict__ d1,
                                              const float4* __restrict__ d2,
                                              float* __restrict__ part2,
                                              unsigned* __restrict__ dd8) {
    int idx = blockIdx.x * 256 + threadIdx.x;          // 0..262143
    if (idx < 256 * BB) part2[idx] = 0.0f;
    if (blockIdx.x == 0 && threadIdx.x < 64)
        dd8[(size_t)ZROW * 64 + threadIdx.x] = 0u;     // sentinel row = zeros
    float4 a = d1[idx], b = d2[idx];
    dd8[idx] = pack4fp8(a.x - b.x, a.y - b.y, a.z - b.z, a.w - b.w);
}

// ---------------------------------------------------------------------------
// k_fused (R16 base + paired gather): 2048 blocks x 4 waves, one wave/row.
// Scan row (nt float4, 6.2 TB/s pattern) -> ballot compaction into per-wave
// LDS u16 list, sentinel-padded to x8 -> PAIRED dwordx2 gathers: one VMEM
// instruction serves TWO nnz rows (lanes 0-31 row i / 32-63 row i+1, 8B/lane)
// — halves gather instruction count (R20 post-mortem: instruction cadence is
// the only untested axis of the invariant ~17 us gather wall).
// Halves combined via shfl_xor(32) before wgt*|.|; half-0 lanes write s_part.
// ---------------------------------------------------------------------------
__global__ __launch_bounds__(256, 4) void k_fused(
        const nfloat4* __restrict__ st4,
        const unsigned* __restrict__ dd8,
        const float* __restrict__ param,
        const int*   __restrict__ parents,
        float* __restrict__ part2) {
    __shared__ unsigned short s_idx[4][CAP];
    __shared__ float s_part[BB];
    const int tid  = threadIdx.x;
    const int wave = tid >> 6;
    const int lane = tid & 63;
    unsigned short* buf = s_idx[wave];

    s_part[tid] = 0.0f;
    __syncthreads();

    const int m = blockIdx.x * 4 + wave;
    if (m < MM) {
        // ---- scan + compact ----------------------------------------------
        int c = 0;
        #pragma unroll
        for (int h = 0; h < 2; ++h) {
            const nfloat4* base = st4 + (size_t)m * (NN / 4) + h * (NN / 8);
            nfloat4 v0 = __builtin_nontemporal_load(base + lane);
            nfloat4 v1 = __builtin_nontemporal_load(base + 64  + lane);
            nfloat4 v2 = __builtin_nontemporal_load(base + 128 + lane);
            nfloat4 v3 = __builtin_nontemporal_load(base + 192 + lane);
            nfloat4 v4 = __builtin_nontemporal_load(base + 256 + lane);
            nfloat4 v5 = __builtin_nontemporal_load(base + 320 + lane);
            nfloat4 v6 = __builtin_nontemporal_load(base + 384 + lane);
            nfloat4 v7 = __builtin_nontemporal_load(base + 448 + lane);

            const int cb = h * (NN / 2);
            #define SITE(val, col)                                          \
            {                                                               \
                unsigned long long mk = __ballot((val) != 0.0f);            \
                if ((val) != 0.0f)                                          \
                    buf[c + prefix_lt(mk)] = (unsigned short)(col);         \
                c += __popcll(mk);                                          \
            }
            #define QUAD(v, cb0)                                            \
                SITE(v.x, (cb0))     SITE(v.y, (cb0) + 1)                   \
                SITE(v.z, (cb0) + 2) SITE(v.w, (cb0) + 3)
            QUAD(v0, cb + (lane)       * 4)
            QUAD(v1, cb + (64  + lane) * 4)
            QUAD(v2, cb + (128 + lane) * 4)
            QUAD(v3, cb + (192 + lane) * 4)
            QUAD(v4, cb + (256 + lane) * 4)
            QUAD(v5, cb + (320 + lane) * 4)
            QUAD(v6, cb + (384 + lane) * 4)
            QUAD(v7, cb + (448 + lane) * 4)
            #undef QUAD
            #undef SITE
        }
        // pad to multiple of 8 with sentinel zero-row indices
        const int cpad = (c + 7) & ~7;
        if (lane < cpad - c) buf[c + lane] = (unsigned short)ZROW;
        __builtin_amdgcn_wave_barrier();

        // ---- paired gather: 2 nnz rows per dwordx2 instruction -----------
        const int half = lane >> 5;        // 0: row i, 1: row i+1
        const int sub  = lane & 31;        // col group: cols sub*8..sub*8+7
        float a0 = 0.f, a1 = 0.f, a2 = 0.f, a3 = 0.f;
        float a4 = 0.f, a5 = 0.f, a6 = 0.f, a7 = 0.f;
#ifdef HW_FP8
        #define DEC(u, j0, j1, j2, j3)                                       \
        {                                                                    \
            f32x2 lo = __builtin_amdgcn_cvt_pk_f32_fp8((int)(u), false);     \
            f32x2 hi = __builtin_amdgcn_cvt_pk_f32_fp8((int)(u), true);      \
            j0 += lo.x; j1 += lo.y; j2 += hi.x; j3 += hi.y;                  \
        }
#else
        #define DEC(u, j0, j1, j2, j3)                                       \
        {                                                                    \
            __hip_fp8_e4m3 q0, q1, q2, q3;                                   \
            q0.__x = (unsigned char)(u);                                     \
            q1.__x = (unsigned char)((u) >> 8);                              \
            q2.__x = (unsigned char)((u) >> 16);                             \
            q3.__x = (unsigned char)((u) >> 24);                             \
            j0 += (float)q0; j1 += (float)q1; j2 += (float)q2; j3 += (float)q3; \
        }
#endif
        #define ACC2(g) { DEC(g.x, a0, a1, a2, a3) DEC(g.y, a4, a5, a6, a7) }
        for (int i = 0; i < cpad; i += 8) {
            unsigned n0 = buf[i + 0 + half];
            unsigned n1 = buf[i + 2 + half];
            unsigned n2 = buf[i + 4 + half];
            unsigned n3 = buf[i + 6 + half];
            uint2 g0 = *(const uint2*)(dd8 + n0 * 64u + sub * 2u);
            uint2 g1 = *(const uint2*)(dd8 + n1 * 64u + sub * 2u);
            uint2 g2 = *(const uint2*)(dd8 + n2 * 64u + sub * 2u);
            uint2 g3 = *(const uint2*)(dd8 + n3 * 64u + sub * 2u);
            ACC2(g0) ACC2(g1) ACC2(g2) ACC2(g3)
        }
        #undef ACC2
        #undef DEC

        // combine halves (lane l and l^32 hold the same cols), then wgt*|.|
        a0 += __shfl_xor(a0, 32, 64);  a1 += __shfl_xor(a1, 32, 64);
        a2 += __shfl_xor(a2, 32, 64);  a3 += __shfl_xor(a3, 32, 64);
        a4 += __shfl_xor(a4, 32, 64);  a5 += __shfl_xor(a5, 32, 64);
        a6 += __shfl_xor(a6, 32, 64);  a7 += __shfl_xor(a7, 32, 64);

        if (half == 0) {
            const float wgt = param[parents[m]] - param[m];
            atomicAdd(&s_part[sub * 8 + 0], wgt * fabsf(a0));
            atomicAdd(&s_part[sub * 8 + 1], wgt * fabsf(a1));
            atomicAdd(&s_part[sub * 8 + 2], wgt * fabsf(a2));
            atomicAdd(&s_part[sub * 8 + 3], wgt * fabsf(a3));
            atomicAdd(&s_part[sub * 8 + 4], wgt * fabsf(a4));
            atomicAdd(&s_part[sub * 8 + 5], wgt * fabsf(a5));
            atomicAdd(&s_part[sub * 8 + 6], wgt * fabsf(a6));
            atomicAdd(&s_part[sub * 8 + 7], wgt * fabsf(a7));
        }
    }
    __syncthreads();
    atomicAdd(&part2[(size_t)(blockIdx.x & 255) * BB + tid], s_part[tid]);
}

// ---------------------------------------------------------------------------
// k_finalize: 1024 threads; (sl,b) sums 64 of 256 part2 rows 8-deep; LDS-
// reduce s-slices; out = sum_b (ot[b]-0.5*w1[b])^2.
// ---------------------------------------------------------------------------
__global__ __launch_bounds__(1024) void k_finalize(const float* __restrict__ part2,
                                                   const float* __restrict__ ot,
                                                   float* __restrict__ out) {
    __shared__ float s_red[4][BB];
    __shared__ float s_sq[16];
    const int tid = threadIdx.x;
    const int sl = tid >> 8, b = tid & 255;

    float a0 = 0.f, a1 = 0.f, a2 = 0.f, a3 = 0.f;
    float a4 = 0.f, a5 = 0.f, a6 = 0.f, a7 = 0.f;
    #pragma unroll
    for (int jj = 0; jj < 64; jj += 8) {
        int row = sl * 64 + jj;
        a0 += part2[(row    ) * BB + b];
        a1 += part2[(row + 1) * BB + b];
        a2 += part2[(row + 2) * BB + b];
        a3 += part2[(row + 3) * BB + b];
        a4 += part2[(row + 4) * BB + b];
        a5 += part2[(row + 5) * BB + b];
        a6 += part2[(row + 6) * BB + b];
        a7 += part2[(row + 7) * BB + b];
    }
    s_red[sl][b] = ((a0 + a1) + (a2 + a3)) + ((a4 + a5) + (a6 + a7));
    __syncthreads();

    float v = 0.0f;
    if (sl == 0) {
        float w1 = (s_red[0][b] + s_red[1][b]) + (s_red[2][b] + s_red[3][b]);
        float e = ot[b] - 0.5f * w1;
        v = e * e;
    }
    #pragma unroll
    for (int off = 32; off > 0; off >>= 1) v += __shfl_down(v, off, 64);
    if ((tid & 63) == 0) s_sq[tid >> 6] = v;
    __syncthreads();
    if (tid == 0) out[0] = (s_sq[0] + s_sq[1]) + (s_sq[2] + s_sq[3]);
}

// ---------------------------------------------------------------------------
extern "C" void kernel_launch(void* const* d_in, const int* in_sizes, int n_in,
                              void* d_out, int out_size, void* d_ws, size_t ws_size,
                              hipStream_t stream) {
    const float* d1      = (const float*)d_in[0];
    const float* d2      = (const float*)d_in[1];
    const float* ot      = (const float*)d_in[2];
    const float* subtree = (const float*)d_in[3];
    const float* param   = (const float*)d_in[4];
    const int*   parents = (const int*)d_in[5];

    char* wsb = (char*)d_ws;
    float* part2  = (float*)wsb;                        // 256 KB
    unsigned* dd8 = (unsigned*)(wsb + 256 * BB * 4);    // 1 MB + sentinel row

    k_prep<<<1024, 256, 0, stream>>>((const float4*)d1, (const float4*)d2,
                                     part2, dd8);
    k_fused<<<2048, 256, 0, stream>>>((const nfloat4*)subtree, dd8,
                                      param, parents, part2);
    k_finalize<<<1, 1024, 0, stream>>>(part2, ot, (float*)d_out);
}